// Round 13
// baseline (54.078 us; speedup 1.0000x reference)
//
#include <hip/hip_runtime.h>
#include <stdint.h>

#define BB 2
#define DD 64
#define HH 128
#define WW 128
#define NVOX (DD*HH*WW)        // 2^20 per batch
#define TOTAL (BB*NVOX)        // 2097152
#define HBINS 36868            // > max finite dsq (36227)
#define EGRID 256              // one block per (slice, dir)
#define CAP (1<<21)            // residual list capacity (covers worst case)

__device__ __forceinline__ int aload(const int* p)
{
    return __hip_atomic_load(p, __ATOMIC_RELAXED, __HIP_MEMORY_SCOPE_AGENT);
}

// ---------- float-based exact fallback (tail only, ~never executed) --------
__device__ __forceinline__ bool getf(const float* __restrict__ v, int b, int z, int y, int x)
{
    return v[((size_t)((b*DD + z)*HH + y) << 7) + x] > 0.5f;
}

__device__ bool is_edge_f(const float* __restrict__ v, int b, int z, int y, int x)
{
    if (!getf(v,b,z,y,x)) return false;
    if (x==0||x==WW-1||y==0||y==HH-1||z==0||z==DD-1) return true;
    return !(getf(v,b,z,y,x-1) && getf(v,b,z,y,x+1) && getf(v,b,z,y-1,x) &&
             getf(v,b,z,y+1,x) && getf(v,b,z-1,y,x) && getf(v,b,z+1,y,x));
}

__device__ int slow_d2_f(const float* __restrict__ v, int b, int z, int y, int x)
{
    int best = 0x7FFFFFFF;
    for (int r = 2; r <= 127; ++r) {
        if (best <= r * r) break;
        for (int dz = -r; dz <= r; ++dz) {
            int zz = z + dz; if (zz < 0 || zz >= DD) continue;
            for (int dy = -r; dy <= r; ++dy) {
                int yy = y + dy; if (yy < 0 || yy >= HH) continue;
                int cheb = max(abs(dz), abs(dy));
                if (cheb == r) {
                    for (int dx = -r; dx <= r; ++dx) {
                        int xx = x + dx; if (xx < 0 || xx >= WW) continue;
                        if (is_edge_f(v, b, zz, yy, xx))
                            best = min(best, dz*dz + dy*dy + dx*dx);
                    }
                } else {
                    for (int t2 = 0; t2 < 2; ++t2) {
                        int dx = t2 ? r : -r;
                        int xx = x + dx; if (xx < 0 || xx >= WW) continue;
                        if (is_edge_f(v, b, zz, yy, xx))
                            best = min(best, dz*dz + dy*dy + dx*dx);
                    }
                }
            }
        }
    }
    return best;
}

// ---------- mono kernel: pack + edges + cube-distance + hist + tail --------
__global__ __launch_bounds__(1024)
void hd95_kernel(const float* __restrict__ pred, const float* __restrict__ targ,
                 int* __restrict__ hot, int* __restrict__ done,
                 int* __restrict__ listCnt, int* __restrict__ list,
                 int* __restrict__ bigh, float* __restrict__ out)
{
    __shared__ uint16_t ownm[3][1024];   // own mask slices  z-1..z+1 (bit words)
    __shared__ uint16_t othm[5][1024];   // other mask slices z-2..z+2
    __shared__ uint16_t tedge[3][1024];  // other EDGE slices z-1..z+1
    __shared__ int lh[4];
    __shared__ int lastflag;
    __shared__ int gmax[4];

    int B = blockIdx.x, tid = threadIdx.x;
    // XCD-contiguous swizzle: XCD = B%8 gets logical ids (B%8)*32 .. +31
    int u = (B & 7) * 32 + (B >> 3);
    int dir = u & 1;
    int bz  = u >> 1;                    // b*DD + z
    int b = bz >> 6, z = bz & (DD - 1);
    const float* ownf = dir ? targ : pred;   // dir0: E = pred edges
    const float* othf = dir ? pred : targ;   // dir0: distances to targ edges

    int wv = tid >> 6, lane = tid & 63;  // wave, lane
    if (tid < 4) lh[tid] = 0;

    // ---- pack 8 slices from floats into LDS bit-words (coalesced + shfl) --
    for (int s = 0; s < 8; ++s) {
        int zs = (s < 3) ? (z + s - 1) : (z + s - 5);
        const float* src = (s < 3) ? ownf : othf;
        uint16_t* dst = (s < 3) ? ownm[s] : othm[s - 3];
        if (zs >= 0 && zs < DD) {
            const float4* s4 = (const float4*)(src + ((size_t)(b*DD + zs) << 14));
            #pragma unroll
            for (int r = 0; r < 4; ++r) {
                float4 f = s4[wv*256 + r*64 + lane];
                uint32_t v = (uint32_t)(f.x > 0.5f)        | ((uint32_t)(f.y > 0.5f) << 1)
                           | ((uint32_t)(f.z > 0.5f) << 2) | ((uint32_t)(f.w > 0.5f) << 3);
                v |= (uint32_t)__shfl_xor((int)v, 1, 64) << 4;  // even lanes: 8 bits
                v |= (uint32_t)__shfl_xor((int)v, 2, 64) << 8;  // lanes%4==0: 16 bits
                int word = __shfl((int)v, (lane & 15) * 4, 64);
                if (lane < 16) dst[wv*64 + r*16 + lane] = (uint16_t)word;
            }
        } else {
            #pragma unroll
            for (int r = 0; r < 4; ++r)
                if (lane < 16) dst[wv*64 + r*16 + lane] = 0;
        }
    }
    __syncthreads();

    int w = tid, y = w >> 3, wx = w & 7;

    // phase A: other-surface edge words for dz in {-1,0,1}
    #pragma unroll
    for (int dzi = 0; dzi < 3; ++dzi) {
        uint32_t c = othm[dzi + 1][w];
        uint32_t l = wx > 0 ? othm[dzi + 1][w - 1] : 0;
        uint32_t r = wx < 7 ? othm[dzi + 1][w + 1] : 0;
        uint32_t ext = (l >> 15) | (c << 1) | ((r & 1u) << 17);
        uint32_t m = (ext >> 1) & 0xFFFFu, L = ext & 0xFFFFu, R = (ext >> 2) & 0xFFFFu;
        uint32_t ym = y > 0   ? othm[dzi + 1][w - 8] : 0;
        uint32_t yp = y < 127 ? othm[dzi + 1][w + 8] : 0;
        uint32_t zm = othm[dzi][w], zp = othm[dzi + 2][w];
        uint32_t er = m & L & R & ym & yp & zm & zp;
        tedge[dzi][w] = (uint16_t)(m & ~er);
    }

    // E: own-surface edge word
    uint32_t E;
    {
        uint32_t c = ownm[1][w];
        uint32_t l = wx > 0 ? ownm[1][w - 1] : 0;
        uint32_t r = wx < 7 ? ownm[1][w + 1] : 0;
        uint32_t ext = (l >> 15) | (c << 1) | ((r & 1u) << 17);
        uint32_t m = (ext >> 1) & 0xFFFFu, L = ext & 0xFFFFu, R = (ext >> 2) & 0xFFFFu;
        uint32_t ym = y > 0   ? ownm[1][w - 8] : 0;
        uint32_t yp = y < 127 ? ownm[1][w + 8] : 0;
        uint32_t zm = ownm[0][w], zp = ownm[2][w];
        E = m & ~(m & L & R & ym & yp & zm & zp);
    }
    __syncthreads();   // tedge ready

    // phase B: M0..M3 = "has oth-edge at d^2 = 0/1/2/3" per voxel
    uint32_t M0 = 0, M1 = 0, M2 = 0, M3 = 0;
    #pragma unroll
    for (int dzi = 0; dzi < 3; ++dzi) {
        #pragma unroll
        for (int dyy = -1; dyy <= 1; ++dyy) {
            int yy = y + dyy;
            uint32_t c = 0, l = 0, r = 0;
            if (yy >= 0 && yy < HH) {
                int w2 = (yy << 3) + wx;
                c = tedge[dzi][w2];
                l = wx > 0 ? tedge[dzi][w2 - 1] : 0;
                r = wx < 7 ? tedge[dzi][w2 + 1] : 0;
            }
            uint32_t ext = (l >> 15) | (c << 1) | ((r & 1u) << 17);
            uint32_t s0 = (ext >> 1) & 0xFFFFu;                      // dx = 0
            uint32_t s1 = (ext & 0xFFFFu) | ((ext >> 2) & 0xFFFFu);  // dx = +-1
            int a = (dzi == 1 ? 0 : 1) + (dyy == 0 ? 0 : 1);
            if (a == 0)      { M0 |= s0; M1 |= s1; }
            else if (a == 1) { M1 |= s0; M2 |= s1; }
            else             { M2 |= s0; M3 |= s1; }
        }
    }

    uint32_t rem = E;
    int c0 = __popc(rem & M0); rem &= ~M0;
    int c1 = __popc(rem & M1); rem &= ~M1;
    int c2 = __popc(rem & M2); rem &= ~M2;
    int c3 = __popc(rem & M3); rem &= ~M3;

    int g = b * 2 + dir;

    // residual voxels (expected ~0): append to list, resolved in tail
    while (rem) {
        int i = __builtin_ctz(rem); rem &= rem - 1;
        int x = wx * 16 + i;
        int pos = atomicAdd(listCnt, 1);
        if (pos < CAP) list[pos] = g | (z << 2) | (y << 8) | (x << 15);
    }

    // wave reduce the 4 hot counters, then one LDS add per wave
    #pragma unroll
    for (int o = 1; o < 64; o <<= 1) {
        c0 += __shfl_xor(c0, o, 64);
        c1 += __shfl_xor(c1, o, 64);
        c2 += __shfl_xor(c2, o, 64);
        c3 += __shfl_xor(c3, o, 64);
    }
    if (lane == 0) {
        if (c0) atomicAdd(&lh[0], c0);
        if (c1) atomicAdd(&lh[1], c1);
        if (c2) atomicAdd(&lh[2], c2);
        if (c3) atomicAdd(&lh[3], c3);
    }
    __syncthreads();
    if (tid < 4) {
        int v = lh[tid];
        int slot = bz & 7;             // spread global flush across 8 shadows
        if (v) atomicAdd(&hot[(g * 8 + slot) * 4 + tid], v);
    }
    // drain this block's flush atomics (syncthreads implies vmcnt(0) per wave)
    __syncthreads();
    if (tid == 0) {
        int old = __hip_atomic_fetch_add(done, 1, __ATOMIC_RELAXED,
                                         __HIP_MEMORY_SCOPE_AGENT);
        lastflag = (old == EGRID - 1);
    }
    __syncthreads();
    if (!lastflag) return;

    // ------------- last block only: residual resolve + percentile ---------
    int nL = aload(listCnt); if (nL > CAP) nL = CAP;
    if (tid < 4) gmax[tid] = 3;
    __syncthreads();
    if (nL > 0) {
        for (int t = tid; t < 4 * HBINS; t += 1024) bigh[t] = 0;
        __syncthreads();
        for (int i2 = tid; i2 < nL; i2 += 1024) {
            int e = list[i2];
            int gg = e & 3, zz = (e >> 2) & 63, yy = (e >> 8) & 127, xx = (e >> 15) & 127;
            const float* vf = (gg & 1) ? pred : targ;   // oth float volume for this g
            int d2 = slow_d2_f(vf, gg >> 1, zz, yy, xx);
            if (d2 >= HBINS) d2 = HBINS - 1;
            atomicAdd(&bigh[(size_t)gg * HBINS + d2], 1);
            atomicMax(&gmax[gg], d2);
        }
        __syncthreads();
    }
    if (tid >= 256) return;
    {
        int gg = tid >> 6;
        int mb = gmax[gg];

        // pass 1: total count n over bins [0..mb]
        int n = 0;
        for (int cc = 0; cc <= mb; cc += 64) {
            int bin = cc + lane;
            int cnt = 0;
            if (bin <= mb) {
                if (bin < 4) {
                    #pragma unroll
                    for (int s = 0; s < 8; ++s) cnt += aload(&hot[(gg * 8 + s) * 4 + bin]);
                }
                if (nL) cnt += aload(&bigh[(size_t)gg * HBINS + bin]);
            }
            #pragma unroll
            for (int o = 1; o < 64; o <<= 1) cnt += __shfl_xor(cnt, o, 64);
            n += cnt;
        }

        float pos = 0.95f * (float)(n - 1);
        float fpos = floorf(pos);
        int lo = (int)fpos;
        int nm1 = n - 1; if (nm1 < 0) nm1 = 0;
        if (lo < 0) lo = 0;
        if (lo > nm1) lo = nm1;
        int hi = lo + 1; if (hi > nm1) hi = nm1;
        float frac = pos - fpos;

        // pass 2: rank select
        int basec = 0, sel0 = 0, sel1 = 0;
        bool f0 = false, f1 = false;
        for (int cc = 0; cc <= mb && !(f0 && f1); cc += 64) {
            int bin = cc + lane;
            int cnt = 0;
            if (bin <= mb) {
                if (bin < 4) {
                    #pragma unroll
                    for (int s = 0; s < 8; ++s) cnt += aload(&hot[(gg * 8 + s) * 4 + bin]);
                }
                if (nL) cnt += aload(&bigh[(size_t)gg * HBINS + bin]);
            }
            int inc = cnt;
            #pragma unroll
            for (int o = 1; o < 64; o <<= 1) {
                int t = __shfl_up(inc, o, 64);
                if (lane >= o) inc += t;
            }
            int exc = inc - cnt;
            unsigned long long b0 = __ballot(!f0 && lo >= basec + exc && lo < basec + inc);
            if (b0) { sel0 = cc + (__ffsll(b0) - 1); f0 = true; }
            unsigned long long b1 = __ballot(!f1 && hi >= basec + exc && hi < basec + inc);
            if (b1) { sel1 = cc + (__ffsll(b1) - 1); f1 = true; }
            basec += __shfl(inc, 63, 64);
        }
        if (lane == 0) {
            float a = sqrtf((float)sel0);
            float bv = sqrtf((float)sel1);
            float val = a + frac * (bv - a);
            atomicMax((int*)out + (gg >> 1), __float_as_int(val));  // val>=0
        }
    }
}

extern "C" void kernel_launch(void* const* d_in, const int* in_sizes, int n_in,
                              void* d_out, int out_size, void* d_ws, size_t ws_size,
                              hipStream_t stream)
{
    const float* pred = (const float*)d_in[0];
    const float* targ = (const float*)d_in[1];
    float* out = (float*)d_out;

    int* hot     = (int*)d_ws;            // 128 ints (4 g x 8 slots x 4 bins)
    int* done    = hot + 128;             // 1 int
    int* listCnt = done + 1;              // 1 int
    int* list    = listCnt + 1;           // CAP ints (residual voxels)
    int* bigh    = list + CAP;            // 4*HBINS ints (tail-only)

    hipMemsetAsync(hot, 0, 130 * sizeof(int), stream);
    hd95_kernel<<<EGRID, 1024, 0, stream>>>(pred, targ, hot, done,
                                            listCnt, list, bigh, out);
}